// Round 1
// baseline (214.275 us; speedup 1.0000x reference)
//
#include <hip/hip_runtime.h>

#define L_SEQ 2048
#define D_DIM 768
#define N_ST 16
#define NB 4
#define NJ 33   // 16 B + 16 C + 1 s1

__device__ __forceinline__ float fast_exp2(float x) {
#if __has_builtin(__builtin_amdgcn_exp2f)
  return __builtin_amdgcn_exp2f(x);
#else
  return __expf(x * 0.69314718055994531f);
#endif
}

__device__ __forceinline__ float softplus_f(float v) {
  float e = __expf(v);
  float l = __logf(1.0f + e);
  return (v > 15.0f) ? v : l;
}

// ---------------------------------------------------------------------------
// Kernel A: BC33[bl*33 + j] = dot(x[bl,:], Wrow_j) + bias_j
//   j in [0,32): W_bc rows (B then C), j == 32: W_1 row (-> s1)
// One wave handles 4 consecutive (b,l) rows; lanes cover d (12 each).
// ---------------------------------------------------------------------------
__global__ __launch_bounds__(256) void k_proj(
    const float* __restrict__ x, const float* __restrict__ W_bc,
    const float* __restrict__ b_bc, const float* __restrict__ W_1,
    const float* __restrict__ b_1, float* __restrict__ BC33) {
  const int lane = threadIdx.x & 63;
  const int wave = threadIdx.x >> 6;
  const int bl0 = blockIdx.x * 16 + wave * 4;
  const float* x0 = x + (size_t)bl0 * D_DIM;

  float xv[4][12];
#pragma unroll
  for (int t = 0; t < 4; ++t)
#pragma unroll
    for (int k = 0; k < 12; ++k)
      xv[t][k] = x0[t * D_DIM + k * 64 + lane];

  float r0 = 0.f, r1 = 0.f, r2 = 0.f, r3 = 0.f;
  for (int j = 0; j < NJ; ++j) {
    const float* wr = (j < 32) ? (W_bc + j * D_DIM) : W_1;
    float a0 = 0.f, a1 = 0.f, a2 = 0.f, a3 = 0.f;
#pragma unroll
    for (int k = 0; k < 12; ++k) {
      float wv = wr[k * 64 + lane];
      a0 = fmaf(xv[0][k], wv, a0);
      a1 = fmaf(xv[1][k], wv, a1);
      a2 = fmaf(xv[2][k], wv, a2);
      a3 = fmaf(xv[3][k], wv, a3);
    }
#pragma unroll
    for (int off = 32; off >= 1; off >>= 1) {
      a0 += __shfl_xor(a0, off);
      a1 += __shfl_xor(a1, off);
      a2 += __shfl_xor(a2, off);
      a3 += __shfl_xor(a3, off);
    }
    float bias = (j < 32) ? b_bc[j] : b_1[0];
    if (lane == j) { r0 = a0 + bias; r1 = a1 + bias; r2 = a2 + bias; r3 = a3 + bias; }
  }
  if (lane < NJ) {
    BC33[(size_t)(bl0 + 0) * NJ + lane] = r0;
    BC33[(size_t)(bl0 + 1) * NJ + lane] = r1;
    BC33[(size_t)(bl0 + 2) * NJ + lane] = r2;
    BC33[(size_t)(bl0 + 3) * NJ + lane] = r3;
  }
}

// ---------------------------------------------------------------------------
// Pass 1: per-chunk local scan with h0 = 0. Emits P (prod of dA over chunk)
// and H (chunk-end state). Thread = one (b, chunk, d) column, 16 n-states in
// registers. P/H layout: [(b*NC + c)*D + d]*16 + n.
// ---------------------------------------------------------------------------
__global__ __launch_bounds__(256) void k_scan1(
    const float* __restrict__ x, const float* __restrict__ A_log,
    const float* __restrict__ W_d, const float* __restrict__ b_d,
    const float* __restrict__ BC33, float* __restrict__ P,
    float* __restrict__ H, int NC, int Lc) {
  const int t = blockIdx.x * 256 + threadIdx.x;
  const int d = t % D_DIM;
  const int c = (t / D_DIM) % NC;
  const int b = t / (D_DIM * NC);

  const float wd = W_d[d], bd = b_d[d];
  float Aln[N_ST];
#pragma unroll
  for (int n = 0; n < N_ST; ++n)
    Aln[n] = -__expf(A_log[d * N_ST + n]) * 1.44269504088896f;  // A * log2(e)

  float p[N_ST], h[N_ST];
#pragma unroll
  for (int n = 0; n < N_ST; ++n) { p[n] = 1.0f; h[n] = 0.0f; }

  const int l0 = c * Lc;
  const float* bc = BC33 + (size_t)(b * L_SEQ + l0) * NJ;
  const float* xp = x + (size_t)(b * L_SEQ + l0) * D_DIM + d;

  for (int l = 0; l < Lc; ++l) {
    float s1 = bc[32];                       // uniform -> scalar load
    float delta = softplus_f(fmaf(s1, wd, bd));
    float xv = xp[0];
    float f = delta * xv;
#pragma unroll
    for (int n = 0; n < N_ST; ++n) {
      float dA = fast_exp2(delta * Aln[n]);
      p[n] *= dA;
      h[n] = fmaf(dA, h[n], f * bc[n]);
    }
    bc += NJ; xp += D_DIM;
  }

  size_t base = ((size_t)(b * NC + c) * D_DIM + d) * N_ST;
  float4* P4 = (float4*)(P + base);
  float4* H4 = (float4*)(H + base);
#pragma unroll
  for (int q = 0; q < 4; ++q) {
    P4[q] = make_float4(p[4*q], p[4*q+1], p[4*q+2], p[4*q+3]);
    H4[q] = make_float4(h[4*q], h[4*q+1], h[4*q+2], h[4*q+3]);
  }
}

// ---------------------------------------------------------------------------
// Pass 2: inter-chunk combine. Thread = one (b,d,n) state; serial over NC
// chunks: HIN[c] = h_in; h_in = P[c]*h_in + H[c].
// ---------------------------------------------------------------------------
__global__ __launch_bounds__(256) void k_combine(
    const float* __restrict__ P, const float* __restrict__ H,
    float* __restrict__ HIN, int NC) {
  const int t = blockIdx.x * 256 + threadIdx.x;     // 0 .. B*D*N-1
  const int tl = t % (D_DIM * N_ST);
  const int b = t / (D_DIM * N_ST);
  float h = 0.0f;
  for (int c = 0; c < NC; ++c) {
    size_t idx = (size_t)(b * NC + c) * (D_DIM * N_ST) + tl;
    HIN[idx] = h;
    h = fmaf(P[idx], h, H[idx]);
  }
}

// ---------------------------------------------------------------------------
// Pass 3: re-run the scan starting from HIN, emit y.
// ---------------------------------------------------------------------------
__global__ __launch_bounds__(256) void k_scan2(
    const float* __restrict__ x, const float* __restrict__ A_log,
    const float* __restrict__ W_d, const float* __restrict__ b_d,
    const float* __restrict__ BC33, const float* __restrict__ HIN,
    float* __restrict__ out, int NC, int Lc) {
  const int t = blockIdx.x * 256 + threadIdx.x;
  const int d = t % D_DIM;
  const int c = (t / D_DIM) % NC;
  const int b = t / (D_DIM * NC);

  const float wd = W_d[d], bd = b_d[d];
  float Aln[N_ST];
#pragma unroll
  for (int n = 0; n < N_ST; ++n)
    Aln[n] = -__expf(A_log[d * N_ST + n]) * 1.44269504088896f;

  float h[N_ST];
  size_t base = ((size_t)(b * NC + c) * D_DIM + d) * N_ST;
  const float4* HIN4 = (const float4*)(HIN + base);
#pragma unroll
  for (int q = 0; q < 4; ++q) {
    float4 v = HIN4[q];
    h[4*q] = v.x; h[4*q+1] = v.y; h[4*q+2] = v.z; h[4*q+3] = v.w;
  }

  const int l0 = c * Lc;
  const float* bc = BC33 + (size_t)(b * L_SEQ + l0) * NJ;
  const float* xp = x + (size_t)(b * L_SEQ + l0) * D_DIM + d;
  float* op = out + (size_t)(b * L_SEQ + l0) * D_DIM + d;

  for (int l = 0; l < Lc; ++l) {
    float s1 = bc[32];
    float delta = softplus_f(fmaf(s1, wd, bd));
    float xv = xp[0];
    float f = delta * xv;
    float y = 0.0f;
#pragma unroll
    for (int n = 0; n < N_ST; ++n) {
      float dA = fast_exp2(delta * Aln[n]);
      h[n] = fmaf(dA, h[n], f * bc[n]);
      y = fmaf(h[n], bc[16 + n], y);
    }
    op[0] = y;
    bc += NJ; xp += D_DIM; op += D_DIM;
  }
}

// ---------------------------------------------------------------------------
extern "C" void kernel_launch(void* const* d_in, const int* in_sizes, int n_in,
                              void* d_out, int out_size, void* d_ws, size_t ws_size,
                              hipStream_t stream) {
  const float* x     = (const float*)d_in[0];
  const float* A_log = (const float*)d_in[1];
  const float* W_bc  = (const float*)d_in[2];
  const float* b_bc  = (const float*)d_in[3];
  const float* W_1   = (const float*)d_in[4];
  const float* b_1   = (const float*)d_in[5];
  const float* W_d   = (const float*)d_in[6];
  const float* b_d   = (const float*)d_in[7];
  float* out = (float*)d_out;
  float* ws  = (float*)d_ws;

  // pick chunk count by workspace budget: BC33 (270336 f) + 3 * (49152*NC) f
  int NC = 4;
  const int cands[4] = {64, 32, 16, 8};
  for (int i = 0; i < 4; ++i) {
    size_t need = (270336ull + 3ull * 49152ull * cands[i]) * 4ull;
    if (ws_size >= need) { NC = cands[i]; break; }
  }
  const int Lc = L_SEQ / NC;

  float* BC33 = ws;
  float* P    = ws + 270336;
  float* H    = P + (size_t)49152 * NC;
  float* HIN  = H + (size_t)49152 * NC;

  k_proj<<<512, 256, 0, stream>>>(x, W_bc, b_bc, W_1, b_1, BC33);
  k_scan1<<<12 * NC, 256, 0, stream>>>(x, A_log, W_d, b_d, BC33, P, H, NC, Lc);
  k_combine<<<192, 256, 0, stream>>>(P, H, HIN, NC);
  k_scan2<<<12 * NC, 256, 0, stream>>>(x, A_log, W_d, b_d, BC33, HIN, out, NC, Lc);
}

// Round 2
// 187.083 us; speedup vs baseline: 1.1453x; 1.1453x over previous
//
#include <hip/hip_runtime.h>

#define L_SEQ 2048
#define D_DIM 768
#define N_ST 16
#define NB 4
#define NJ 33   // 16 B + 16 C + 1 s1

__device__ __forceinline__ float fast_exp2(float x) {
#if __has_builtin(__builtin_amdgcn_exp2f)
  return __builtin_amdgcn_exp2f(x);
#else
  return __expf(x * 0.69314718055994531f);
#endif
}

__device__ __forceinline__ float softplus_f(float v) {
  float e = __expf(v);
  float l = __logf(1.0f + e);
  return (v > 15.0f) ? v : l;
}

// ---------------------------------------------------------------------------
// Kernel A: BC33[bl*33 + j] = dot(x[bl,:], Wrow_j) + bias_j
// One wave handles 4 consecutive (b,l) rows; lanes cover d (12 each).
// ---------------------------------------------------------------------------
__global__ __launch_bounds__(256) void k_proj(
    const float* __restrict__ x, const float* __restrict__ W_bc,
    const float* __restrict__ b_bc, const float* __restrict__ W_1,
    const float* __restrict__ b_1, float* __restrict__ BC33) {
  const int lane = threadIdx.x & 63;
  const int wave = threadIdx.x >> 6;
  const int bl0 = blockIdx.x * 16 + wave * 4;
  const float* x0 = x + (size_t)bl0 * D_DIM;

  float xv[4][12];
#pragma unroll
  for (int t = 0; t < 4; ++t)
#pragma unroll
    for (int k = 0; k < 12; ++k)
      xv[t][k] = x0[t * D_DIM + k * 64 + lane];

  float r0 = 0.f, r1 = 0.f, r2 = 0.f, r3 = 0.f;
  for (int j = 0; j < NJ; ++j) {
    const float* wr = (j < 32) ? (W_bc + j * D_DIM) : W_1;
    float a0 = 0.f, a1 = 0.f, a2 = 0.f, a3 = 0.f;
#pragma unroll
    for (int k = 0; k < 12; ++k) {
      float wv = wr[k * 64 + lane];
      a0 = fmaf(xv[0][k], wv, a0);
      a1 = fmaf(xv[1][k], wv, a1);
      a2 = fmaf(xv[2][k], wv, a2);
      a3 = fmaf(xv[3][k], wv, a3);
    }
#pragma unroll
    for (int off = 32; off >= 1; off >>= 1) {
      a0 += __shfl_xor(a0, off);
      a1 += __shfl_xor(a1, off);
      a2 += __shfl_xor(a2, off);
      a3 += __shfl_xor(a3, off);
    }
    float bias = (j < 32) ? b_bc[j] : b_1[0];
    if (lane == j) { r0 = a0 + bias; r1 = a1 + bias; r2 = a2 + bias; r3 = a3 + bias; }
  }
  if (lane < NJ) {
    BC33[(size_t)(bl0 + 0) * NJ + lane] = r0;
    BC33[(size_t)(bl0 + 1) * NJ + lane] = r1;
    BC33[(size_t)(bl0 + 2) * NJ + lane] = r2;
    BC33[(size_t)(bl0 + 3) * NJ + lane] = r3;
  }
}

// ---------------------------------------------------------------------------
// Pass 1: per-chunk local scan, h0 = 0. Emits P = prod(dA) (via exp2(Aln*sum
// delta)) and chunk-end state H. Block indexing is blockIdx-derived so b, c,
// l0 are wave-uniform -> BC33 reads scalarize to s_load.
// Grid: NB * NC * 3 blocks; block = 256 threads covering 256 d's.
// ---------------------------------------------------------------------------
template <int LC>
__global__ __launch_bounds__(256) void k_scan1(
    const float* __restrict__ x, const float* __restrict__ A_log,
    const float* __restrict__ W_d, const float* __restrict__ b_d,
    const float* __restrict__ BC33, float* __restrict__ P,
    float* __restrict__ H, int NC) {
  const int cb = blockIdx.x % 3;                 // which 256-d slice
  const int c  = (blockIdx.x / 3) % NC;
  const int b  = blockIdx.x / (3 * NC);
  const int d  = cb * 256 + threadIdx.x;

  const float wd = W_d[d], bd = b_d[d];
  float Aln[N_ST];
#pragma unroll
  for (int n = 0; n < N_ST; ++n)
    Aln[n] = -__expf(A_log[d * N_ST + n]) * 1.44269504088896f;  // A * log2(e)

  float h[N_ST];
#pragma unroll
  for (int n = 0; n < N_ST; ++n) h[n] = 0.0f;
  float dsum = 0.0f;

  const int l0 = c * LC;
  const float* bc = BC33 + (size_t)(b * L_SEQ + l0) * NJ;
  const float* xp = x + (size_t)(b * L_SEQ + l0) * D_DIM + d;

#pragma unroll 8
  for (int l = 0; l < LC; ++l) {
    float s1 = bc[l * NJ + 32];                  // scalar load
    float delta = softplus_f(fmaf(s1, wd, bd));
    float xv = xp[(size_t)l * D_DIM];
    float f = delta * xv;
    dsum += delta;
#pragma unroll
    for (int n = 0; n < N_ST; ++n) {
      float dA = fast_exp2(delta * Aln[n]);
      h[n] = fmaf(dA, h[n], f * bc[l * NJ + n]);
    }
  }

  size_t base = ((size_t)(b * NC + c) * D_DIM + d) * N_ST;
  float4* P4 = (float4*)(P + base);
  float4* H4 = (float4*)(H + base);
#pragma unroll
  for (int q = 0; q < 4; ++q) {
    P4[q] = make_float4(fast_exp2(Aln[4*q+0] * dsum), fast_exp2(Aln[4*q+1] * dsum),
                        fast_exp2(Aln[4*q+2] * dsum), fast_exp2(Aln[4*q+3] * dsum));
    H4[q] = make_float4(h[4*q], h[4*q+1], h[4*q+2], h[4*q+3]);
  }
}

// ---------------------------------------------------------------------------
// Pass 2: inter-chunk combine, in-place: H[c] becomes the INCOMING state for
// chunk c. Thread = one (b,d,n) state.
// ---------------------------------------------------------------------------
__global__ __launch_bounds__(256) void k_combine(
    const float* __restrict__ P, float* __restrict__ H, int NC) {
  const int b  = blockIdx.x / 48;                // 48 blocks per batch
  const int tl = (blockIdx.x % 48) * 256 + threadIdx.x;
  float h = 0.0f;
#pragma unroll 4
  for (int c = 0; c < NC; ++c) {
    size_t idx = (size_t)(b * NC + c) * (D_DIM * N_ST) + tl;
    float hold = H[idx];
    float p = P[idx];
    H[idx] = h;                                  // incoming state for chunk c
    h = fmaf(p, h, hold);
  }
}

// ---------------------------------------------------------------------------
// Pass 3: re-run the scan starting from H (now = incoming state), emit y.
// ---------------------------------------------------------------------------
template <int LC>
__global__ __launch_bounds__(256) void k_scan2(
    const float* __restrict__ x, const float* __restrict__ A_log,
    const float* __restrict__ W_d, const float* __restrict__ b_d,
    const float* __restrict__ BC33, const float* __restrict__ HIN,
    float* __restrict__ out, int NC) {
  const int cb = blockIdx.x % 3;
  const int c  = (blockIdx.x / 3) % NC;
  const int b  = blockIdx.x / (3 * NC);
  const int d  = cb * 256 + threadIdx.x;

  const float wd = W_d[d], bd = b_d[d];
  float Aln[N_ST];
#pragma unroll
  for (int n = 0; n < N_ST; ++n)
    Aln[n] = -__expf(A_log[d * N_ST + n]) * 1.44269504088896f;

  float h[N_ST];
  size_t base = ((size_t)(b * NC + c) * D_DIM + d) * N_ST;
  const float4* HIN4 = (const float4*)(HIN + base);
#pragma unroll
  for (int q = 0; q < 4; ++q) {
    float4 v = HIN4[q];
    h[4*q] = v.x; h[4*q+1] = v.y; h[4*q+2] = v.z; h[4*q+3] = v.w;
  }

  const int l0 = c * LC;
  const float* bc = BC33 + (size_t)(b * L_SEQ + l0) * NJ;
  const float* xp = x + (size_t)(b * L_SEQ + l0) * D_DIM + d;
  float* op = out + (size_t)(b * L_SEQ + l0) * D_DIM + d;

#pragma unroll 8
  for (int l = 0; l < LC; ++l) {
    float s1 = bc[l * NJ + 32];
    float delta = softplus_f(fmaf(s1, wd, bd));
    float xv = xp[(size_t)l * D_DIM];
    float f = delta * xv;
    float y = 0.0f;
#pragma unroll
    for (int n = 0; n < N_ST; ++n) {
      float dA = fast_exp2(delta * Aln[n]);
      h[n] = fmaf(dA, h[n], f * bc[l * NJ + n]);
      y = fmaf(h[n], bc[l * NJ + 16 + n], y);
    }
    op[(size_t)l * D_DIM] = y;
  }
}

// ---------------------------------------------------------------------------
extern "C" void kernel_launch(void* const* d_in, const int* in_sizes, int n_in,
                              void* d_out, int out_size, void* d_ws, size_t ws_size,
                              hipStream_t stream) {
  const float* x     = (const float*)d_in[0];
  const float* A_log = (const float*)d_in[1];
  const float* W_bc  = (const float*)d_in[2];
  const float* b_bc  = (const float*)d_in[3];
  const float* W_1   = (const float*)d_in[4];
  const float* b_1   = (const float*)d_in[5];
  const float* W_d   = (const float*)d_in[6];
  const float* b_d   = (const float*)d_in[7];
  float* out = (float*)d_out;
  float* ws  = (float*)d_ws;

  // workspace: BC33 (270336 f) + P (49152*NC f) + H (49152*NC f)
  int NC = 8;
  const int cands[4] = {128, 64, 32, 16};
  for (int i = 0; i < 4; ++i) {
    size_t need = (270336ull + 2ull * 49152ull * cands[i]) * 4ull;
    if (ws_size >= need) { NC = cands[i]; break; }
  }

  float* BC33 = ws;
  float* P    = ws + 270336;
  float* H    = P + (size_t)49152 * NC;

  k_proj<<<512, 256, 0, stream>>>(x, W_bc, b_bc, W_1, b_1, BC33);

  const int gs = 3 * NB * NC;   // scan grid
  switch (NC) {
    case 128:
      k_scan1<16><<<gs, 256, 0, stream>>>(x, A_log, W_d, b_d, BC33, P, H, NC);
      k_combine<<<192, 256, 0, stream>>>(P, H, NC);
      k_scan2<16><<<gs, 256, 0, stream>>>(x, A_log, W_d, b_d, BC33, H, out, NC);
      break;
    case 64:
      k_scan1<32><<<gs, 256, 0, stream>>>(x, A_log, W_d, b_d, BC33, P, H, NC);
      k_combine<<<192, 256, 0, stream>>>(P, H, NC);
      k_scan2<32><<<gs, 256, 0, stream>>>(x, A_log, W_d, b_d, BC33, H, out, NC);
      break;
    case 32:
      k_scan1<64><<<gs, 256, 0, stream>>>(x, A_log, W_d, b_d, BC33, P, H, NC);
      k_combine<<<192, 256, 0, stream>>>(P, H, NC);
      k_scan2<64><<<gs, 256, 0, stream>>>(x, A_log, W_d, b_d, BC33, H, out, NC);
      break;
    case 16:
      k_scan1<128><<<gs, 256, 0, stream>>>(x, A_log, W_d, b_d, BC33, P, H, NC);
      k_combine<<<192, 256, 0, stream>>>(P, H, NC);
      k_scan2<128><<<gs, 256, 0, stream>>>(x, A_log, W_d, b_d, BC33, H, out, NC);
      break;
    default:
      k_scan1<256><<<gs, 256, 0, stream>>>(x, A_log, W_d, b_d, BC33, P, H, NC);
      k_combine<<<192, 256, 0, stream>>>(P, H, NC);
      k_scan2<256><<<gs, 256, 0, stream>>>(x, A_log, W_d, b_d, BC33, H, out, NC);
      break;
  }
}

// Round 3
// 179.433 us; speedup vs baseline: 1.1942x; 1.0426x over previous
//
#include <hip/hip_runtime.h>

#define L_SEQ 2048
#define D_DIM 768
#define N_ST 16
#define NB 4
#define NJ 33   // 16 B + 16 C + 1 s1
#define NROWS (NB * L_SEQ)          // 8192
#define PROJ_ELEMS (NROWS * NJ)     // 270336

// proj GEMM tiling
#define DSPLIT 8
#define DSEG (D_DIM / DSPLIT)       // 96
#define DK 32
#define NCHUNK (DSEG / DK)          // 3
#define RB 128                      // rows per block
#define XST 132                     // xs_t row stride (pad 128 -> 132, mult of 4)
#define WST 64                      // ws_t row stride (8 jg * 8 slots)

__device__ __forceinline__ float fast_exp2(float x) {
#if __has_builtin(__builtin_amdgcn_exp2f)
  return __builtin_amdgcn_exp2f(x);
#else
  return __expf(x * 0.69314718055994531f);
#endif
}

__device__ __forceinline__ float softplus_f(float v) {
  float e = __expf(v);
  float l = __logf(1.0f + e);
  return (v > 15.0f) ? v : l;
}

// ---------------------------------------------------------------------------
// Projection GEMM, K-split 8 ways. Block = 256 threads = 128 rows x 40 jslots.
// jslot s = jg*8+k  <->  j = jg + 8*k (k<5). Partial sums to PBC[ds][row][33].
// LDS tiles stored transposed so compute reads are ds_read_b128.
// ---------------------------------------------------------------------------
__global__ __launch_bounds__(256) void k_proj_gemm(
    const float* __restrict__ x, const float* __restrict__ W_bc,
    const float* __restrict__ W_1, float* __restrict__ PBC) {
  __shared__ float xs_t[DK * XST];   // [dk][row]
  __shared__ float ws_t[DK * WST];   // [dk][jslot]

  const int ds  = blockIdx.x % DSPLIT;
  const int rb0 = (blockIdx.x / DSPLIT) * RB;
  const int dbase = ds * DSEG;
  const int tid = threadIdx.x;

  // compute mapping
  const int rg = tid & 31;          // row group: rows rg*4 .. rg*4+3
  const int jg = tid >> 5;          // j group: j = jg + 8k

  float acc[4][5];
#pragma unroll
  for (int i = 0; i < 4; ++i)
#pragma unroll
    for (int k = 0; k < 5; ++k) acc[i][k] = 0.0f;

  // x-loader mapping: thread -> (row, half)
  const int lrow = tid >> 1;
  const int lhalf = (tid & 1) * 16;
  const float* xg_row = x + (size_t)(rb0 + lrow) * D_DIM + dbase + lhalf;

  for (int ch = 0; ch < NCHUNK; ++ch) {
    const int dc = dbase + ch * DK;
    // ---- stage x tile (transposed) ----
    float4 xv[4];
#pragma unroll
    for (int q = 0; q < 4; ++q)
      xv[q] = *(const float4*)(xg_row + ch * DK + q * 4);
    // ---- stage W tile (transposed, slot-remapped) ----
    float wv[8];
    int widx[8];
#pragma unroll
    for (int u = 0; u < 8; ++u) {
      int idx = tid + u * 256;                 // 0 .. 2047
      int dk = idx >> 6, slot = idx & 63;
      int wjg = slot >> 3, wk = slot & 7;
      int j = wjg + 8 * wk;
      float v = 0.0f;
      if (wk < 5) {
        if (j < 32)       v = W_bc[(size_t)j * D_DIM + dc + dk];
        else if (j == 32) v = W_1[dc + dk];
      }
      wv[u] = v; widx[u] = dk * WST + slot;
    }
    __syncthreads();   // safe to overwrite LDS from previous chunk
#pragma unroll
    for (int q = 0; q < 4; ++q) {
      xs_t[(lhalf + q * 4 + 0) * XST + lrow] = xv[q].x;
      xs_t[(lhalf + q * 4 + 1) * XST + lrow] = xv[q].y;
      xs_t[(lhalf + q * 4 + 2) * XST + lrow] = xv[q].z;
      xs_t[(lhalf + q * 4 + 3) * XST + lrow] = xv[q].w;
    }
#pragma unroll
    for (int u = 0; u < 8; ++u) ws_t[widx[u]] = wv[u];
    __syncthreads();
    // ---- compute ----
#pragma unroll 8
    for (int dk = 0; dk < DK; ++dk) {
      float4 xr = *(const float4*)&xs_t[dk * XST + rg * 4];
      float4 wr = *(const float4*)&ws_t[dk * WST + jg * 8];
      float w4  = ws_t[dk * WST + jg * 8 + 4];
      float xa[4] = {xr.x, xr.y, xr.z, xr.w};
      float wa[5] = {wr.x, wr.y, wr.z, wr.w, w4};
#pragma unroll
      for (int i = 0; i < 4; ++i)
#pragma unroll
        for (int k = 0; k < 5; ++k)
          acc[i][k] = fmaf(xa[i], wa[k], acc[i][k]);
    }
  }

  // ---- write partials ----
  float* pb = PBC + (size_t)ds * PROJ_ELEMS;
#pragma unroll
  for (int i = 0; i < 4; ++i) {
    int row = rb0 + rg * 4 + i;
#pragma unroll
    for (int k = 0; k < 5; ++k) {
      int j = jg + 8 * k;
      if (k < 4 || jg == 0) pb[(size_t)row * NJ + j] = acc[i][k];
    }
  }
}

// ---------------------------------------------------------------------------
// Sum the 8 K-split partials + bias -> BC33.
// ---------------------------------------------------------------------------
__global__ __launch_bounds__(256) void k_proj_reduce(
    const float* __restrict__ PBC, const float* __restrict__ b_bc,
    const float* __restrict__ b_1, float* __restrict__ BC33) {
  const int idx = blockIdx.x * 256 + threadIdx.x;   // grid sized exactly
  const int j = idx % NJ;
  float s = 0.0f;
#pragma unroll
  for (int k = 0; k < DSPLIT; ++k) s += PBC[(size_t)k * PROJ_ELEMS + idx];
  s += (j < 32) ? b_bc[j] : b_1[0];
  BC33[idx] = s;
}

// ---------------------------------------------------------------------------
// Pass 1: per-chunk local scan, h0 = 0. Emits chunk-end state H and the
// per-column delta sum DS (combine recomputes P = exp2(Aln*DS) on the fly).
// ---------------------------------------------------------------------------
template <int LC>
__global__ __launch_bounds__(256) void k_scan1(
    const float* __restrict__ x, const float* __restrict__ A_log,
    const float* __restrict__ W_d, const float* __restrict__ b_d,
    const float* __restrict__ BC33, float* __restrict__ DS,
    float* __restrict__ H, int NC) {
  const int cb = blockIdx.x % 3;
  const int c  = (blockIdx.x / 3) % NC;
  const int b  = blockIdx.x / (3 * NC);
  const int d  = cb * 256 + threadIdx.x;

  const float wd = W_d[d], bd = b_d[d];
  float Aln[N_ST];
#pragma unroll
  for (int n = 0; n < N_ST; ++n)
    Aln[n] = -__expf(A_log[d * N_ST + n]) * 1.44269504088896f;  // A * log2(e)

  float h[N_ST];
#pragma unroll
  for (int n = 0; n < N_ST; ++n) h[n] = 0.0f;
  float dsum = 0.0f;

  const int l0 = c * LC;
  const float* bc = BC33 + (size_t)(b * L_SEQ + l0) * NJ;
  const float* xp = x + (size_t)(b * L_SEQ + l0) * D_DIM + d;

#pragma unroll 8
  for (int l = 0; l < LC; ++l) {
    float s1 = bc[l * NJ + 32];                  // scalar load
    float delta = softplus_f(fmaf(s1, wd, bd));
    float xv = xp[(size_t)l * D_DIM];
    float f = delta * xv;
    dsum += delta;
#pragma unroll
    for (int n = 0; n < N_ST; ++n) {
      float dA = fast_exp2(delta * Aln[n]);
      h[n] = fmaf(dA, h[n], f * bc[l * NJ + n]);
    }
  }

  DS[((size_t)b * NC + c) * D_DIM + d] = dsum;
  size_t base = ((size_t)(b * NC + c) * D_DIM + d) * N_ST;
  float4* H4 = (float4*)(H + base);
#pragma unroll
  for (int q = 0; q < 4; ++q)
    H4[q] = make_float4(h[4*q], h[4*q+1], h[4*q+2], h[4*q+3]);
}

// ---------------------------------------------------------------------------
// Pass 2: inter-chunk combine, in-place: H[c] becomes the INCOMING state.
// P recomputed from DS. Thread = one (b,d,n) state.
// ---------------------------------------------------------------------------
__global__ __launch_bounds__(256) void k_combine(
    const float* __restrict__ A_log, const float* __restrict__ DS,
    float* __restrict__ H, int NC) {
  const int b  = blockIdx.x / 48;
  const int tl = (blockIdx.x % 48) * 256 + threadIdx.x;   // 0..12287
  const int d = tl >> 4, n = tl & 15;
  const float Aln = -__expf(A_log[d * N_ST + n]) * 1.44269504088896f;

  const float* dsp = DS + (size_t)b * NC * D_DIM + d;
  float* Hp = H + (size_t)b * NC * (D_DIM * N_ST) + tl;

  float h = 0.0f;
  float ds_c = dsp[0];
  float hold = Hp[0];
#pragma unroll 4
  for (int c = 0; c < NC; ++c) {
    float ds_n = 0.0f, hold_n = 0.0f;
    if (c + 1 < NC) {
      ds_n   = dsp[(size_t)(c + 1) * D_DIM];
      hold_n = Hp[(size_t)(c + 1) * (D_DIM * N_ST)];
    }
    float p = fast_exp2(Aln * ds_c);
    Hp[(size_t)c * (D_DIM * N_ST)] = h;
    h = fmaf(p, h, hold);
    ds_c = ds_n; hold = hold_n;
  }
}

// ---------------------------------------------------------------------------
// Pass 3: re-run the scan starting from H (incoming state), emit y.
// ---------------------------------------------------------------------------
template <int LC>
__global__ __launch_bounds__(256) void k_scan2(
    const float* __restrict__ x, const float* __restrict__ A_log,
    const float* __restrict__ W_d, const float* __restrict__ b_d,
    const float* __restrict__ BC33, const float* __restrict__ HIN,
    float* __restrict__ out, int NC) {
  const int cb = blockIdx.x % 3;
  const int c  = (blockIdx.x / 3) % NC;
  const int b  = blockIdx.x / (3 * NC);
  const int d  = cb * 256 + threadIdx.x;

  const float wd = W_d[d], bd = b_d[d];
  float Aln[N_ST];
#pragma unroll
  for (int n = 0; n < N_ST; ++n)
    Aln[n] = -__expf(A_log[d * N_ST + n]) * 1.44269504088896f;

  float h[N_ST];
  size_t base = ((size_t)(b * NC + c) * D_DIM + d) * N_ST;
  const float4* HIN4 = (const float4*)(HIN + base);
#pragma unroll
  for (int q = 0; q < 4; ++q) {
    float4 v = HIN4[q];
    h[4*q] = v.x; h[4*q+1] = v.y; h[4*q+2] = v.z; h[4*q+3] = v.w;
  }

  const int l0 = c * LC;
  const float* bc = BC33 + (size_t)(b * L_SEQ + l0) * NJ;
  const float* xp = x + (size_t)(b * L_SEQ + l0) * D_DIM + d;
  float* op = out + (size_t)(b * L_SEQ + l0) * D_DIM + d;

#pragma unroll 8
  for (int l = 0; l < LC; ++l) {
    float s1 = bc[l * NJ + 32];
    float delta = softplus_f(fmaf(s1, wd, bd));
    float xv = xp[(size_t)l * D_DIM];
    float f = delta * xv;
    float y = 0.0f;
#pragma unroll
    for (int n = 0; n < N_ST; ++n) {
      float dA = fast_exp2(delta * Aln[n]);
      h[n] = fmaf(dA, h[n], f * bc[l * NJ + n]);
      y = fmaf(h[n], bc[l * NJ + 16 + n], y);
    }
    op[(size_t)l * D_DIM] = y;
  }
}

// ---------------------------------------------------------------------------
extern "C" void kernel_launch(void* const* d_in, const int* in_sizes, int n_in,
                              void* d_out, int out_size, void* d_ws, size_t ws_size,
                              hipStream_t stream) {
  const float* x     = (const float*)d_in[0];
  const float* A_log = (const float*)d_in[1];
  const float* W_bc  = (const float*)d_in[2];
  const float* b_bc  = (const float*)d_in[3];
  const float* W_1   = (const float*)d_in[4];
  const float* b_1   = (const float*)d_in[5];
  const float* W_d   = (const float*)d_in[6];
  const float* b_d   = (const float*)d_in[7];
  float* out = (float*)d_out;
  float* ws  = (float*)d_ws;

  // workspace (floats): BC33 270336 + PBC 8*270336 + DS 3072*NC + H 49152*NC
  int NC = 8;
  const int cands[4] = {128, 64, 32, 16};
  for (int i = 0; i < 4; ++i) {
    size_t need = (9ull * PROJ_ELEMS + (3072ull + 49152ull) * cands[i]) * 4ull;
    if (ws_size >= need) { NC = cands[i]; break; }
  }

  float* BC33 = ws;
  float* PBC  = ws + PROJ_ELEMS;
  float* DSb  = PBC + (size_t)DSPLIT * PROJ_ELEMS;
  float* H    = DSb + (size_t)3072 * NC;

  k_proj_gemm<<<(NROWS / RB) * DSPLIT, 256, 0, stream>>>(x, W_bc, W_1, PBC);
  k_proj_reduce<<<PROJ_ELEMS / 256, 256, 0, stream>>>(PBC, b_bc, b_1, BC33);

  const int gs = 3 * NB * NC;
  switch (NC) {
    case 128:
      k_scan1<16><<<gs, 256, 0, stream>>>(x, A_log, W_d, b_d, BC33, DSb, H, NC);
      k_combine<<<192, 256, 0, stream>>>(A_log, DSb, H, NC);
      k_scan2<16><<<gs, 256, 0, stream>>>(x, A_log, W_d, b_d, BC33, H, out, NC);
      break;
    case 64:
      k_scan1<32><<<gs, 256, 0, stream>>>(x, A_log, W_d, b_d, BC33, DSb, H, NC);
      k_combine<<<192, 256, 0, stream>>>(A_log, DSb, H, NC);
      k_scan2<32><<<gs, 256, 0, stream>>>(x, A_log, W_d, b_d, BC33, H, out, NC);
      break;
    case 32:
      k_scan1<64><<<gs, 256, 0, stream>>>(x, A_log, W_d, b_d, BC33, DSb, H, NC);
      k_combine<<<192, 256, 0, stream>>>(A_log, DSb, H, NC);
      k_scan2<64><<<gs, 256, 0, stream>>>(x, A_log, W_d, b_d, BC33, H, out, NC);
      break;
    case 16:
      k_scan1<128><<<gs, 256, 0, stream>>>(x, A_log, W_d, b_d, BC33, DSb, H, NC);
      k_combine<<<192, 256, 0, stream>>>(A_log, DSb, H, NC);
      k_scan2<128><<<gs, 256, 0, stream>>>(x, A_log, W_d, b_d, BC33, H, out, NC);
      break;
    default:
      k_scan1<256><<<gs, 256, 0, stream>>>(x, A_log, W_d, b_d, BC33, DSb, H, NC);
      k_combine<<<192, 256, 0, stream>>>(A_log, DSb, H, NC);
      k_scan2<256><<<gs, 256, 0, stream>>>(x, A_log, W_d, b_d, BC33, H, out, NC);
      break;
  }
}